// Round 7
// baseline (412.865 us; speedup 1.0000x reference)
//
#include <hip/hip_runtime.h>
#include <hip/hip_bf16.h>

#define BB 16
#define SS 8192
#define DD 256

typedef __attribute__((ext_vector_type(8))) short bf16x8;
typedef __attribute__((ext_vector_type(4))) short bf16x4;
typedef __attribute__((ext_vector_type(4))) float f32x4;

__device__ __forceinline__ unsigned short f2bf(float f) {
    union { float f; unsigned u; } v; v.f = f;
    unsigned r = v.u + 0x7FFFu + ((v.u >> 16) & 1u);   // round-to-nearest-even
    return (unsigned short)(r >> 16);
}
__device__ __forceinline__ float bf2f(unsigned short u) {
    union { unsigned u; float f; } cv; cv.u = (unsigned)u << 16; return cv.f;
}
__device__ __forceinline__ unsigned pack2(float a, float b) {
    return (unsigned)f2bf(a) | ((unsigned)f2bf(b) << 16);
}
// split w into hi+lo bf16 (residual ~2^-18 relative)
__device__ __forceinline__ void split_bf(float w, unsigned short& hi, unsigned short& lo) {
    hi = f2bf(w);
    lo = f2bf(w - bf2f(hi));
}

#define LTS 40   // slab row stride in shorts: 80B = 16B*5 -> aligned b128 frag reads

// ---------------------------------------------------------------------------
// moment (unchanged, proven): partial[kc][b][d][e] = sum_s x[b,s,d]*x[b,s,e].
// Grid (8 kc, 2 nh, 16 b) x 512. 8 waves, dbuf LDS slab, prefetch 2 ahead.
// ---------------------------------------------------------------------------
__global__ __launch_bounds__(512) void moment_kernel(const float* __restrict__ x,
                                                     float* __restrict__ partial,
                                                     float* __restrict__ sumx8) {
    const int kc = blockIdx.x;
    const int nh = blockIdx.y;
    const int b  = blockIdx.z;
    const float* xb = x + ((size_t)b * SS + (size_t)kc * 1024) * DD;

    __shared__ unsigned short Lt0[256 * LTS];
    __shared__ unsigned short Lt1[256 * LTS];
    __shared__ float csh[8 * 256];

    const int tid  = threadIdx.x;
    const int wave = tid >> 6;
    const int lane = tid & 63;
    const int lc   = lane & 15;
    const int lq   = lane >> 4;

    const int mrow0 = (wave & 3) * 64;
    const int ncol0 = nh * 128 + (wave >> 2) * 64;

    const int sg = tid >> 6;
    const int dg = tid & 63;
    const float* xt = xb + (size_t)(sg * 4) * DD + dg;

    f32x4 acc[4][4];
#pragma unroll
    for (int mi = 0; mi < 4; ++mi)
#pragma unroll
        for (int ni = 0; ni < 4; ++ni) acc[mi][ni] = (f32x4){0.f, 0.f, 0.f, 0.f};
    float cs[4] = {0.f, 0.f, 0.f, 0.f};

    float va[16], vb[16];

    auto LOAD = [&](float* v, int t) {
#pragma unroll
        for (int i = 0; i < 4; ++i)
#pragma unroll
            for (int j = 0; j < 4; ++j)
                v[i * 4 + j] = xt[(size_t)(t * 32 + i) * DD + 64 * j];
    };
    auto STAGE = [&](const float* v, unsigned short* Lw) {
        if (nh == 0) {
#pragma unroll
            for (int j = 0; j < 4; ++j)
                cs[j] += v[j] + v[4 + j] + v[8 + j] + v[12 + j];
        }
#pragma unroll
        for (int j = 0; j < 4; ++j) {
            uint2 w;
            w.x = pack2(v[j], v[4 + j]);
            w.y = pack2(v[8 + j], v[12 + j]);
            *(uint2*)&Lw[(dg + 64 * j) * LTS + sg * 4] = w;
        }
    };
    auto COMPUTE = [&](const unsigned short* Lr) {
        bf16x8 af[4], bfr[4];
#pragma unroll
        for (int mi = 0; mi < 4; ++mi)
            af[mi] = *(const bf16x8*)&Lr[(mrow0 + mi * 16 + lc) * LTS + lq * 8];
#pragma unroll
        for (int ni = 0; ni < 4; ++ni)
            bfr[ni] = *(const bf16x8*)&Lr[(ncol0 + ni * 16 + lc) * LTS + lq * 8];
#pragma unroll
        for (int mi = 0; mi < 4; ++mi)
#pragma unroll
            for (int ni = 0; ni < 4; ++ni)
                acc[mi][ni] = __builtin_amdgcn_mfma_f32_16x16x32_bf16(
                    af[mi], bfr[ni], acc[mi][ni], 0, 0, 0);
    };

    LOAD(va, 0);
    STAGE(va, Lt0);
    LOAD(vb, 1);
    __syncthreads();

    for (int tt = 0; tt < 16; ++tt) {
        const int t0 = 2 * tt;
        STAGE(vb, Lt1);
        if (t0 < 30) LOAD(va, t0 + 2);
        COMPUTE(Lt0);
        __syncthreads();
        if (t0 + 1 < 31) STAGE(va, Lt0);
        if (t0 + 1 < 30) LOAD(vb, t0 + 3);
        COMPUTE(Lt1);
        __syncthreads();
    }

    float* pp = partial + (size_t)(kc * 16 + b) * DD * DD;
#pragma unroll
    for (int mi = 0; mi < 4; ++mi)
#pragma unroll
        for (int ni = 0; ni < 4; ++ni) {
            const int row = mrow0 + mi * 16 + lq * 4;
            const int col = ncol0 + ni * 16 + lc;
#pragma unroll
            for (int r = 0; r < 4; ++r)
                pp[(size_t)(row + r) * DD + col] = acc[mi][ni][r];
        }

    if (nh == 0) {
        __syncthreads();
#pragma unroll
        for (int j = 0; j < 4; ++j) csh[sg * 256 + dg + 64 * j] = cs[j];
        __syncthreads();
        if (tid < 256) {
            float t0 = 0.f;
#pragma unroll
            for (int g = 0; g < 8; ++g) t0 += csh[g * 256 + tid];
            sumx8[(size_t)(kc * 16 + b) * DD + tid] = t0;
        }
    }
}

// ---------------------------------------------------------------------------
// finalize = stats + sigman fused (one launch instead of two; ~15us gap saved).
// Grid (16 g, 16 b) x 256. Every block redundantly computes mean + tr (cheap);
// block g writes rows d = g*16..g*16+15 of sigma_n into Xa. g==0 also writes
// m and trbuf for apply.
// ---------------------------------------------------------------------------
__global__ __launch_bounds__(256) void finalize_kernel(const float* __restrict__ partial,
                                                       const float* __restrict__ sumx8,
                                                       float* __restrict__ m,
                                                       float* __restrict__ trbuf,
                                                       float* __restrict__ Xa) {
    const int g = blockIdx.x;
    const int b = blockIdx.y;
    const int t = threadIdx.x;

    __shared__ float mean[256];
    __shared__ float red[256];

    float sx = 0.f;
#pragma unroll
    for (int kc = 0; kc < 8; ++kc)
        sx += sumx8[(size_t)(kc * 16 + b) * DD + t];
    const float mu = sx * (1.0f / (float)SS);
    mean[t] = mu;
    if (g == 0) m[b * DD + t] = mu;

    float ds = 0.f;
#pragma unroll
    for (int kc = 0; kc < 8; ++kc)
        ds += partial[((size_t)(kc * 16 + b) * DD + t) * DD + t];
    red[t] = (ds - (float)SS * mu * mu) * (1.0f / (float)(SS - 1));
    __syncthreads();
    for (int off = 128; off > 0; off >>= 1) {
        if (t < off) red[t] += red[t + off];
        __syncthreads();
    }
    const float tr  = red[0];
    const float itr = 1.0f / tr;
    if (g == 0 && t == 0) {
        trbuf[b]      = tr;
        trbuf[16 + b] = rsqrtf(tr);
        trbuf[32 + b] = itr;
    }

    const float sc = (1.0f / (float)(SS - 1)) * itr;
    const float mt = mean[t];
#pragma unroll
    for (int i = 0; i < 16; ++i) {
        const int d = g * 16 + i;
        const float md = mean[d];
        float s = 0.f;
#pragma unroll
        for (int kc = 0; kc < 8; ++kc)
            s += partial[((size_t)(kc * 16 + b) * DD + d) * DD + t];
        Xa[(size_t)b * DD * DD + (size_t)d * DD + t] =
            (s - (float)SS * md * mt) * sc;
    }
}

// ---------------------------------------------------------------------------
// Batched 256^3 matmul via MFMA, split-bf16 fp32 emulation (unchanged, proven).
// ---------------------------------------------------------------------------
#define BTS 72
__global__ __launch_bounds__(256) void bmm_mfma(
    const float* __restrict__ A0, const float* __restrict__ B0, float* __restrict__ C0,
    int ta0, int tb0,
    const float* __restrict__ A1, const float* __restrict__ B1, float* __restrict__ C1,
    int ta1, int tb1) {
    const int by  = blockIdx.y;
    const int set = by >> 4;
    const int bb  = by & 15;
    const float* Ag = (set ? A1 : A0) + (size_t)bb * DD * DD;
    const float* Bg = (set ? B1 : B0) + (size_t)bb * DD * DD;
    float*       Cg = (set ? C1 : C0) + (size_t)bb * DD * DD;
    const int TA = set ? ta1 : ta0;
    const int TB = set ? tb1 : tb0;

    const int m0 = (blockIdx.x >> 2) * 64;
    const int n0 = (blockIdx.x & 3) * 64;

    __shared__ unsigned short Ahi[2][64 * BTS];
    __shared__ unsigned short Alo[2][64 * BTS];
    __shared__ unsigned short Bhi[2][64 * BTS];
    __shared__ unsigned short Blo[2][64 * BTS];

    const int tid  = threadIdx.x;
    const int wave = tid >> 6;
    const int lane = tid & 63;
    const int lc = lane & 15, lq = lane >> 4;
    const int mrow0 = (wave & 1) * 32;
    const int ncol0 = (wave >> 1) * 32;

    const int r  = tid >> 2;
    const int kl = (tid & 3) * 4;
    const float* Arow = Ag + (size_t)(m0 + r) * DD + kl;
    const float* Brow = Bg + (size_t)(n0 + r) * DD + kl;

    f32x4 acc[2][2];
#pragma unroll
    for (int mi = 0; mi < 2; ++mi)
#pragma unroll
        for (int ni = 0; ni < 2; ++ni) acc[mi][ni] = (f32x4){0.f, 0.f, 0.f, 0.f};

    float4 va0[4], vb0[4], va1[4], vb1[4];

    auto LOADC = [&](float4* va, float4* vb, int c) {
#pragma unroll
        for (int i = 0; i < 4; ++i) va[i] = *(const float4*)(Arow + c * 64 + i * 16);
#pragma unroll
        for (int i = 0; i < 4; ++i) vb[i] = *(const float4*)(Brow + c * 64 + i * 16);
    };
    auto STAGE_SIDE = [&](const float4* v, unsigned short* Shi, unsigned short* Slo,
                          int c, int gmn, int tflag) {
#pragma unroll
        for (int i = 0; i < 4; ++i) {
            float xv[4] = {v[i].x, v[i].y, v[i].z, v[i].w};
            unsigned short h[4], l[4];
#pragma unroll
            for (int j = 0; j < 4; ++j) {
                float wv = xv[j];
                if (tflag) {
                    const int gk = c * 64 + kl + i * 16 + j;
                    wv = ((gk == gmn) ? 1.5f : 0.0f) - 0.5f * wv;
                }
                split_bf(wv, h[j], l[j]);
            }
            unsigned short* ph = &Shi[r * BTS + kl + i * 16];
            *(unsigned*)&ph[0] = (unsigned)h[0] | ((unsigned)h[1] << 16);
            *(unsigned*)&ph[2] = (unsigned)h[2] | ((unsigned)h[3] << 16);
            unsigned short* pl = &Slo[r * BTS + kl + i * 16];
            *(unsigned*)&pl[0] = (unsigned)l[0] | ((unsigned)l[1] << 16);
            *(unsigned*)&pl[2] = (unsigned)l[2] | ((unsigned)l[3] << 16);
        }
    };
    auto STAGE = [&](const float4* va, const float4* vb, int c, int buf) {
        STAGE_SIDE(va, Ahi[buf], Alo[buf], c, m0 + r, TA);
        STAGE_SIDE(vb, Bhi[buf], Blo[buf], c, n0 + r, TB);
    };
    auto COMPUTE = [&](int buf) {
#pragma unroll
        for (int ks = 0; ks < 2; ++ks) {
            bf16x8 ah[2], al[2], bh[2], bl[2];
#pragma unroll
            for (int mi = 0; mi < 2; ++mi) {
                const int off = (mrow0 + mi * 16 + lc) * BTS + ks * 32 + lq * 8;
                ah[mi] = *(const bf16x8*)&Ahi[buf][off];
                al[mi] = *(const bf16x8*)&Alo[buf][off];
            }
#pragma unroll
            for (int ni = 0; ni < 2; ++ni) {
                const int off = (ncol0 + ni * 16 + lc) * BTS + ks * 32 + lq * 8;
                bh[ni] = *(const bf16x8*)&Bhi[buf][off];
                bl[ni] = *(const bf16x8*)&Blo[buf][off];
            }
#pragma unroll
            for (int mi = 0; mi < 2; ++mi)
#pragma unroll
                for (int ni = 0; ni < 2; ++ni) {
                    acc[mi][ni] = __builtin_amdgcn_mfma_f32_16x16x32_bf16(
                        al[mi], bh[ni], acc[mi][ni], 0, 0, 0);
                    acc[mi][ni] = __builtin_amdgcn_mfma_f32_16x16x32_bf16(
                        ah[mi], bl[ni], acc[mi][ni], 0, 0, 0);
                    acc[mi][ni] = __builtin_amdgcn_mfma_f32_16x16x32_bf16(
                        ah[mi], bh[ni], acc[mi][ni], 0, 0, 0);
                }
        }
    };

    LOADC(va0, vb0, 0);
    LOADC(va1, vb1, 1);
    STAGE(va0, vb0, 0, 0);
    __syncthreads();
#pragma unroll
    for (int cc = 0; cc < 2; ++cc) {
        const int c0 = 2 * cc;
        STAGE(va1, vb1, c0 + 1, 1);
        if (c0 + 2 < 4) LOADC(va0, vb0, c0 + 2);
        COMPUTE(0);
        __syncthreads();
        if (c0 + 2 < 4) STAGE(va0, vb0, c0 + 2, 0);
        if (c0 + 3 < 4) LOADC(va1, vb1, c0 + 3);
        COMPUTE(1);
        __syncthreads();
    }

#pragma unroll
    for (int mi = 0; mi < 2; ++mi)
#pragma unroll
        for (int ni = 0; ni < 2; ++ni) {
            const int row = m0 + mrow0 + mi * 16 + lq * 4;
            const int col = n0 + ncol0 + ni * 16 + lc;
#pragma unroll
            for (int rr = 0; rr < 4; ++rr)
                Cg[(size_t)(row + rr) * DD + col] = acc[mi][ni][rr];
        }
}

// ---------------------------------------------------------------------------
// apply v5: out[b,s,e] = sum_d x[b,s,d]*wm[d,e] - corr[e]. BARRIER-FREE K-loop:
// A-fragment = 8 consecutive k-floats of one x-row per lane -> loaded DIRECT
// from global (2 x float4, 32B aligned) and converted in-register via
// v_cvt_pk_bf16_f32 (__float22bfloat162_rn). No A-slab, no staging barriers;
// waves free-run, x re-reads hit L1/L2/LLC (x = 128MB < 256MB LLC).
// B-slab (wm, rs folded) staged once. LDS 68KB -> 2 blocks/CU.
// Grid (64 st, 2 nh, 16 b) x 256.
// ---------------------------------------------------------------------------
#define BSS 264
__global__ __launch_bounds__(256) void apply_kernel(const float* __restrict__ x,
                                                    const float* __restrict__ P,
                                                    const float* __restrict__ m,
                                                    const float* __restrict__ trbuf,
                                                    float* __restrict__ out) {
    const int st = blockIdx.x;
    const int nh = blockIdx.y;
    const int b  = blockIdx.z;
    const int s0 = st * 128;
    const int n0 = nh * 128;
    const float rs = trbuf[16 + b];
    const float* xb = x + (size_t)b * SS * DD;
    const float* Pb = P + (size_t)b * DD * DD;
    const float* mb = m + b * DD;
    float* ob = out + (size_t)b * SS * DD;

    __shared__ unsigned short Bs[128 * BSS];   // 67.6 KB
    __shared__ float corr2[256];
    __shared__ float corr[128];

    const int tid  = threadIdx.x;
    const int wave = tid >> 6;
    const int lane = tid & 63;
    const int lc = lane & 15, lq = lane >> 4;
    const int mrow0 = (wave & 1) * 64;
    const int ncol0 = (wave >> 1) * 64;

    {   // stage B once (rs folded in); wm[k][n]=wm[n][k] by symmetry
        const int r = tid >> 1, h = tid & 1;
        const float* prow = Pb + (size_t)(n0 + r) * DD + h * 128;
        unsigned short* brow = &Bs[r * BSS + h * 128];
#pragma unroll
        for (int i = 0; i < 32; ++i) {
            float4 pv = *(const float4*)(prow + i * 4);
            *(unsigned*)&brow[i * 4]     = pack2(pv.x * rs, pv.y * rs);
            *(unsigned*)&brow[i * 4 + 2] = pack2(pv.z * rs, pv.w * rs);
        }
    }
    __syncthreads();

    {   // corr[n] = sum_k m[k]*wm[k][n]; k split in halves across 256 threads
        const int n = tid & 127, h = tid >> 7;
        float s = 0.f;
#pragma unroll 8
        for (int k = 0; k < 128; ++k)
            s += mb[h * 128 + k] * bf2f(Bs[n * BSS + h * 128 + k]);
        corr2[tid] = s;
    }
    __syncthreads();
    if (tid < 128) corr[tid] = corr2[tid] + corr2[128 + tid];
    // corr visibility to all waves is ensured by the pre-epilogue barrier.

    f32x4 acc[4][4];
#pragma unroll
    for (int mi = 0; mi < 4; ++mi)
#pragma unroll
        for (int ni = 0; ni < 4; ++ni) acc[mi][ni] = (f32x4){0.f, 0.f, 0.f, 0.f};

    const float* xw = xb + (size_t)(s0 + mrow0 + lc) * DD + lq * 8;
    float4 cA[8], nA[8];

    auto LOADA = [&](float4* v, int t) {
#pragma unroll
        for (int mi = 0; mi < 4; ++mi) {
            const float* p = xw + (size_t)mi * 16 * DD + t * 32;
            v[mi * 2]     = *(const float4*)p;
            v[mi * 2 + 1] = *(const float4*)(p + 4);
        }
    };
    auto STEP = [&](const float4* v, int t) {
        bf16x8 af[4], bfr[4];
#pragma unroll
        for (int mi = 0; mi < 4; ++mi) {
            union { bf16x8 w; __hip_bfloat162 h2[4]; } u;
            u.h2[0] = __float22bfloat162_rn(make_float2(v[mi * 2].x,     v[mi * 2].y));
            u.h2[1] = __float22bfloat162_rn(make_float2(v[mi * 2].z,     v[mi * 2].w));
            u.h2[2] = __float22bfloat162_rn(make_float2(v[mi * 2 + 1].x, v[mi * 2 + 1].y));
            u.h2[3] = __float22bfloat162_rn(make_float2(v[mi * 2 + 1].z, v[mi * 2 + 1].w));
            af[mi] = u.w;
        }
#pragma unroll
        for (int ni = 0; ni < 4; ++ni)
            bfr[ni] = *(const bf16x8*)&Bs[(ncol0 + ni * 16 + lc) * BSS + t * 32 + lq * 8];
#pragma unroll
        for (int mi = 0; mi < 4; ++mi)
#pragma unroll
            for (int ni = 0; ni < 4; ++ni)
                acc[mi][ni] = __builtin_amdgcn_mfma_f32_16x16x32_bf16(
                    af[mi], bfr[ni], acc[mi][ni], 0, 0, 0);
    };

    // K = 256 in 8 steps of 32, no barriers; loads issued one step ahead.
    LOADA(cA, 0);
#pragma unroll
    for (int tt = 0; tt < 4; ++tt) {
        const int t0 = 2 * tt;
        if (t0 + 1 < 8) LOADA(nA, t0 + 1);
        STEP(cA, t0);
        if (t0 + 2 < 8) LOADA(cA, t0 + 2);
        STEP(nA, t0 + 1);
    }

    __syncthreads();   // corr written by waves 0/1 visible to all
#pragma unroll
    for (int mi = 0; mi < 4; ++mi)
#pragma unroll
        for (int ni = 0; ni < 4; ++ni) {
            const int row = s0 + mrow0 + mi * 16 + lq * 4;
            const int col = n0 + ncol0 + ni * 16 + lc;
            const float cv = corr[ncol0 + ni * 16 + lc];
#pragma unroll
            for (int r = 0; r < 4; ++r)
                ob[(size_t)(row + r) * DD + col] = acc[mi][ni][r] - cv;
        }
}

extern "C" void kernel_launch(void* const* d_in, const int* in_sizes, int n_in,
                              void* d_out, int out_size, void* d_ws, size_t ws_size,
                              hipStream_t stream) {
    const float* x = (const float*)d_in[0];
    float* out = (float*)d_out;
    float* ws = (float*)d_ws;

    const size_t MAT = (size_t)BB * DD * DD;        // 1,048,576 floats
    float* partial = ws;                            // 8 * MAT = 32 MB
    float* sumx8 = partial + 8 * MAT;               // 32768
    float* m     = sumx8 + 8 * BB * DD;             // 4096
    float* trbuf = m + BB * DD;                     // 64
    float* Xa    = trbuf + 64;
    float* Xb    = Xa + MAT;
    float* T     = Xb + MAT;
    float* Pa    = T + MAT;
    float* Pb    = Pa + MAT;
    // total ~54.6 MB of workspace

    moment_kernel<<<dim3(8, 2, 16), 512, 0, stream>>>(x, partial, sumx8);
    finalize_kernel<<<dim3(16, 16), 256, 0, stream>>>(partial, sumx8, m, trbuf, Xa);

    // Newton-Schulz: X_{k+1} = X_k W_k^2, P_{k+1} = P_k W_k, W_k = 1.5I - 0.5 X_k
    // (all symmetric, commuting). Independent products fused 2-per-launch.
    bmm_mfma<<<dim3(16, 16), 256, 0, stream>>>(Xa, Xa, T, 1, 1,
                                               Xa, Xa, T, 1, 1);   // T  = W0^2
    bmm_mfma<<<dim3(16, 16), 256, 0, stream>>>(Xa, T, Xb, 0, 0,
                                               Xa, T, Xb, 0, 0);   // X1 = X0*T
    bmm_mfma<<<dim3(16, 32), 256, 0, stream>>>(Xa, Xb, Pa, 1, 1,   // P2 = W0*W1
                                               Xb, Xb, T, 1, 1);   // T  = W1^2
    bmm_mfma<<<dim3(16, 16), 256, 0, stream>>>(Xb, T, Xa, 0, 0,
                                               Xb, T, Xa, 0, 0);   // X2 = X1*T
    bmm_mfma<<<dim3(16, 32), 256, 0, stream>>>(Pa, Xa, Pb, 0, 1,   // P3 = P2*W2
                                               Xa, Xa, T, 1, 1);   // T  = W2^2
    bmm_mfma<<<dim3(16, 16), 256, 0, stream>>>(Xa, T, Xb, 0, 0,
                                               Xa, T, Xb, 0, 0);   // X3 = X2*T
    bmm_mfma<<<dim3(16, 16), 256, 0, stream>>>(Pb, Xb, Pa, 0, 1,
                                               Pb, Xb, Pa, 0, 1);  // P4 = P3*W3

    apply_kernel<<<dim3(64, 2, 16), 256, 0, stream>>>(x, Pa, m, trbuf, out);
}